// Round 10
// baseline (539.106 us; speedup 1.0000x reference)
//
#include <hip/hip_runtime.h>

#define EPS  1e-5f
#define CNTF 409600.0f            // N*T*V
#define XDP_ELEMS 6553600         // per layer: 16384 nt * 400, layout [nt][u][16o]
#define Z_ELEMS   32768000        // 16384 * 2000, layout [nt][v][80ch]

typedef short bf16x8 __attribute__((ext_vector_type(8)));
typedef float f32x4  __attribute__((ext_vector_type(4)));

union FRAG { unsigned int u[4]; bf16x8 v; };

__device__ __forceinline__ float wave_sum(float v) {
#pragma unroll
    for (int off = 32; off > 0; off >>= 1)
        v += __shfl_down(v, off, 64);
    return v;
}

__device__ __forceinline__ float bfu(unsigned int u16) {
    union { unsigned int i; float f; } x;
    x.i = u16 << 16;
    return x.f;
}
__device__ __forceinline__ unsigned int f2bf(float f) {
    union { float f; unsigned int i; } u; u.f = f;
    unsigned int r = u.i + 0x7fff + ((u.i >> 16) & 1);
    return r >> 16;
}
__device__ __forceinline__ unsigned int packbf(float a, float b) {
    return f2bf(a) | (f2bf(b) << 16);
}

// ---- K0: transpose W_down into [c][48] so k_down3 can scalar-load it
__global__ __launch_bounds__(256) void k_prep(const float* __restrict__ Wd,
                                              float* __restrict__ Wtg)
{
    for (int j = threadIdx.x; j < 3072; j += 256) {
        int c = j / 48, k = j - c * 48;
        int l = k / 16, o = k - l * 16;
        Wtg[j] = Wd[l * 1024 + o * 64 + c];
    }
}

// ---- K1: conv_down all 3 layers (bias cancels in BN), bf16 xd + stats.
__global__ __launch_bounds__(256) void k_down3(
    const float* __restrict__ x, const float* __restrict__ Wtg,
    unsigned short* __restrict__ xdp, float* __restrict__ st /*96*/)
{
    __shared__ float bins[96];
    const int tid = threadIdx.x;
    if (tid < 96) bins[tid] = 0.f;
    __syncthreads();

    const int base = (blockIdx.x * 256 + tid) * 2;
    const int n = base / 3200, pb = base - n * 3200;
    const float* xb = x + n * 204800 + pb;

    float acc0[48], acc1[48];
#pragma unroll
    for (int k = 0; k < 48; k++) { acc0[k] = 0.f; acc1[k] = 0.f; }

    for (int c = 0; c < 64; c++) {
        float2 xv = *(const float2*)&xb[c * 3200];
        const float4* wr = (const float4*)(Wtg + c * 48);   // uniform -> s_load
#pragma unroll
        for (int q = 0; q < 12; q++) {
            float4 w = wr[q];
            acc0[4*q+0] += w.x * xv.x;  acc1[4*q+0] += w.x * xv.y;
            acc0[4*q+1] += w.y * xv.x;  acc1[4*q+1] += w.y * xv.y;
            acc0[4*q+2] += w.z * xv.x;  acc1[4*q+2] += w.z * xv.y;
            acc0[4*q+3] += w.w * xv.x;  acc1[4*q+3] += w.w * xv.y;
        }
    }
#pragma unroll
    for (int l = 0; l < 3; l++) {
        unsigned int pk0[8], pk1[8];
#pragma unroll
        for (int h = 0; h < 8; h++) {
            pk0[h] = packbf(acc0[l*16 + 2*h], acc0[l*16 + 2*h + 1]);
            pk1[h] = packbf(acc1[l*16 + 2*h], acc1[l*16 + 2*h + 1]);
        }
        uint4* dst = (uint4*)(xdp + (size_t)l * XDP_ELEMS + (size_t)base * 16);
        dst[0] = make_uint4(pk0[0], pk0[1], pk0[2], pk0[3]);
        dst[1] = make_uint4(pk0[4], pk0[5], pk0[6], pk0[7]);
        dst[2] = make_uint4(pk1[0], pk1[1], pk1[2], pk1[3]);
        dst[3] = make_uint4(pk1[4], pk1[5], pk1[6], pk1[7]);
    }

    const int lane = tid & 63;
#pragma unroll
    for (int k = 0; k < 48; k++) {
        float sv = wave_sum(acc0[k] + acc1[k]);
        float qv = wave_sum(acc0[k] * acc0[k] + acc1[k] * acc1[k]);
        if (lane == 0) { atomicAdd(&bins[k], sv); atomicAdd(&bins[48 + k], qv); }
    }
    __syncthreads();
    if (tid < 96) atomicAdd(&st[tid], bins[tid]);
}

// ---- K2: finalize down affines
__global__ __launch_bounds__(64) void k_findown(
    const float* __restrict__ st, const float* __restrict__ gd,
    const float* __restrict__ betad, float* __restrict__ AC)
{
    int t = threadIdx.x;
    if (t < 48) {
        float m   = st[t] * (1.f / CNTF);
        float var = st[48 + t] * (1.f / CNTF) - m * m;
        float a   = gd[t] * rsqrtf(var + EPS);
        AC[t]      = a;
        AC[48 + t] = betad[t] - a * m;
    }
}

// ---- K3 (MFMA): per-layer z + sub BN stats.
__global__ __launch_bounds__(256, 1) void k_z_mfma(
    const unsigned short* __restrict__ xd,   // [nt][u<25][16c] bf16
    const float* __restrict__ PAl,           // [5][25][25]
    const float* __restrict__ Wsl,           // [80][16]
    const float* __restrict__ Al, const float* __restrict__ Cl,
    unsigned short* __restrict__ zbuf,       // [nt][v<25][80] bf16
    float* __restrict__ stql)                // [160]
{
    __shared__ unsigned short xtile[4][512];      // per-wave raw xd tile (u<=31 x 16c)
    __shared__ unsigned short Mtile[4][32][16];   // per-wave M reshape [v][c]
    __shared__ float bins[160];

    const int tid  = threadIdx.x;
    const int wave = tid >> 6, lane = tid & 63;
    const int lr = lane & 15, lg = lane >> 4;

    // zero ALL of xtile once (tail u>=25 stays 0 forever)
    *(uint4*)&xtile[tid >> 6][(tid & 63) * 8] = make_uint4(0, 0, 0, 0);
    for (int i = tid; i < 160; i += 256) bins[i] = 0.f;
    __syncthreads();

    // persistent B fragments: B(lg,i) = PA[s][v=16t+lr][u=8*lg+i], 0 if oob
    bf16x8 Bfrag[5][2];
#pragma unroll
    for (int s = 0; s < 5; s++)
#pragma unroll
        for (int t = 0; t < 2; t++) {
            FRAG f;
            const int v = t * 16 + lr;
#pragma unroll
            for (int h = 0; h < 4; h++) {
                int u0 = 8 * lg + 2 * h, u1 = u0 + 1;
                float f0 = (v < 25 && u0 < 25) ? PAl[(s * 25 + v) * 25 + u0] : 0.f;
                float f1 = (v < 25 && u1 < 25) ? PAl[(s * 25 + v) * 25 + u1] : 0.f;
                f.u[h] = packbf(f0, f1);
            }
            Bfrag[s][t] = f.v;
        }

    // persistent W fragments: A2(lg,i) = W[s][o=lr][c=8*lg+i], 0 if c>=16
    bf16x8 Wfrag[5];
#pragma unroll
    for (int s = 0; s < 5; s++) {
        FRAG f;
#pragma unroll
        for (int h = 0; h < 4; h++) {
            int c0 = 8 * lg + 2 * h, c1 = c0 + 1;
            float f0 = (c0 < 16) ? Wsl[(s * 16 + lr) * 16 + c0] : 0.f;
            float f1 = (c1 < 16) ? Wsl[(s * 16 + lr) * 16 + c1] : 0.f;
            f.u[h] = packbf(f0, f1);
        }
        Wfrag[s] = f.v;
    }

    const float a_c = Al[lr], c_c = Cl[lr];   // down-BN affine for channel c=lr

    f32x4 sacc[5] = {};
    f32x4 qacc[5] = {};
    const f32x4 zero = {};

    const int wid = blockIdx.x * 4 + wave;    // 4096 waves x 4 nt = 16384
    for (int k = 0; k < 4; k++) {
        const int nt = wid * 4 + k;
        // stage one nt (800B) into the wave's private tile
        if (lane < 50)
            *(uint4*)&xtile[wave][lane * 8] =
                *(const uint4*)(xd + (size_t)nt * 400 + lane * 8);
        __syncthreads();   // staging visible (uniform: all waves, all k)

        // A fragment: lane holds c=lr, u=8*lg+i
        FRAG af;
#pragma unroll
        for (int h = 0; h < 4; h++) {
            int u0 = 8 * lg + 2 * h;
            float x0 = bfu(xtile[wave][u0 * 16 + lr]);
            float x1 = bfu(xtile[wave][(u0 + 1) * 16 + lr]);
            x0 = fmaxf(a_c * x0 + c_c, 0.f);
            x1 = fmaxf(a_c * x1 + c_c, 0.f);
            af.u[h] = packbf(x0, x1);
        }
        const bf16x8 A = af.v;
        unsigned short* zrow = zbuf + (size_t)nt * 2000;

#pragma unroll
        for (int s = 0; s < 5; s++) {
            // step A: M_s tiles (D: col=v=lr, row=c=4*lg+r)
            f32x4 d0 = __builtin_amdgcn_mfma_f32_16x16x32_bf16(A, Bfrag[s][0], zero, 0, 0, 0);
            f32x4 d1 = __builtin_amdgcn_mfma_f32_16x16x32_bf16(A, Bfrag[s][1], zero, 0, 0, 0);
            // reshape via LDS: M [v][c] bf16
            *(uint2*)&Mtile[wave][lr][4 * lg] =
                make_uint2(packbf(d0[0], d0[1]), packbf(d0[2], d0[3]));
            *(uint2*)&Mtile[wave][16 + lr][4 * lg] =
                make_uint2(packbf(d1[0], d1[1]), packbf(d1[2], d1[3]));
            __syncthreads();   // writes -> reads
            // B2: lane holds v=16t+lr, c=8*(lg&1)+i (c>=16 slots: Wfrag zero)
            FRAG b2a, b2b;
            *(uint4*)b2a.u = *(const uint4*)&Mtile[wave][lr][8 * (lg & 1)];
            *(uint4*)b2b.u = *(const uint4*)&Mtile[wave][16 + lr][8 * (lg & 1)];
            __syncthreads();   // reads done before next s overwrites (WAR)
            // step B: Z_s (D: col=v, row=o=4*lg+r)
            f32x4 z0 = __builtin_amdgcn_mfma_f32_16x16x32_bf16(Wfrag[s], b2a.v, zero, 0, 0, 0);
            f32x4 z1 = __builtin_amdgcn_mfma_f32_16x16x32_bf16(Wfrag[s], b2b.v, zero, 0, 0, 0);

            sacc[s] += z0; qacc[s] += z0 * z0;
            unsigned short* zp = zrow + lr * 80 + s * 16 + 4 * lg;
            *(uint2*)zp = make_uint2(packbf(z0[0], z0[1]), packbf(z0[2], z0[3]));
            if (lr < 9) {                         // tile2 valid v = 16..24
                sacc[s] += z1; qacc[s] += z1 * z1;
                *(uint2*)(zp + 1280) =
                    make_uint2(packbf(z1[0], z1[1]), packbf(z1[2], z1[3]));
            }
        }
    }

    // stats: reduce over the 16 v-lanes, then block bins, then global
#pragma unroll
    for (int s = 0; s < 5; s++)
#pragma unroll
        for (int r = 0; r < 4; r++) {
            float sv = sacc[s][r], qv = qacc[s][r];
            sv += __shfl_xor(sv, 1, 64); qv += __shfl_xor(qv, 1, 64);
            sv += __shfl_xor(sv, 2, 64); qv += __shfl_xor(qv, 2, 64);
            sv += __shfl_xor(sv, 4, 64); qv += __shfl_xor(qv, 4, 64);
            sv += __shfl_xor(sv, 8, 64); qv += __shfl_xor(qv, 8, 64);
            if (lr == 0) {
                atomicAdd(&bins[s * 16 + 4 * lg + r], sv);
                atomicAdd(&bins[80 + s * 16 + 4 * lg + r], qv);
            }
        }
    __syncthreads();
    for (int i = tid; i < 160; i += 256) atomicAdd(&stql[i], bins[i]);
}

// ---- K4: apply affine + subset-0 add, RMW acc in d_out; stats on last layer.
// No per-thread output array: values go straight into the LDS transpose tile
// (32 channels per half), so nothing register-heavy crosses a barrier.
template <int FIRST, int LAST>
__global__ __launch_bounds__(256, 2) void k_apply(
    const unsigned short* __restrict__ zbuf, const float* __restrict__ stql,
    const float* __restrict__ gsl, const float* __restrict__ betal,
    float* __restrict__ out, float* __restrict__ stout)
{
    __shared__ float AS[80], CS[80];
    __shared__ float tile[32][208];
    const int tid = threadIdx.x;
    if (tid < 80) {
        float m   = stql[tid] * (1.f / CNTF);
        float var = stql[80 + tid] * (1.f / CNTF) - m * m;
        float a   = gsl[tid] * rsqrtf(var + EPS);
        AS[tid] = a; CS[tid] = betal[tid] - a * m;
    }

    const int nt0 = blockIdx.x * 8, n = nt0 >> 7, t0 = nt0 & 127;
    const int pp = tid / 25;
    const uint4* z8 = (const uint4*)(zbuf + (size_t)(nt0 + pp) * 2000 +
                                     (tid - pp * 25) * 80);

#pragma unroll
    for (int h = 0; h < 2; h++) {
        __syncthreads();   // AS/CS ready (h=0) / prev-half tile reads done (h=1)
        if (tid < 200) {
            // subset-0 base values (recomputed per half; short live range)
            float zb[16];
#pragma unroll
            for (int j = 0; j < 2; j++) {
                uint4 w = z8[j];
                zb[j*8+0] = AS[j*8+0]*bfu(w.x & 0xffffu) + CS[j*8+0];
                zb[j*8+1] = AS[j*8+1]*bfu(w.x >> 16)     + CS[j*8+1];
                zb[j*8+2] = AS[j*8+2]*bfu(w.y & 0xffffu) + CS[j*8+2];
                zb[j*8+3] = AS[j*8+3]*bfu(w.y >> 16)     + CS[j*8+3];
                zb[j*8+4] = AS[j*8+4]*bfu(w.z & 0xffffu) + CS[j*8+4];
                zb[j*8+5] = AS[j*8+5]*bfu(w.z >> 16)     + CS[j*8+5];
                zb[j*8+6] = AS[j*8+6]*bfu(w.w & 0xffffu) + CS[j*8+6];
                zb[j*8+7] = AS[j*8+7]*bfu(w.w >> 16)     + CS[j*8+7];
            }
#pragma unroll
            for (int jj = 0; jj < 4; jj++) {
                const int j = 2 + 4 * h + jj;
                const int g = j * 8 - 16;        // global agg channel 0..63
                const int r = g - 32 * h;        // tile row 0..31
                uint4 w = z8[j];
                tile[r+0][tid] = AS[16+g+0]*bfu(w.x & 0xffffu) + CS[16+g+0] + zb[(g+0)&15];
                tile[r+1][tid] = AS[16+g+1]*bfu(w.x >> 16)     + CS[16+g+1] + zb[(g+1)&15];
                tile[r+2][tid] = AS[16+g+2]*bfu(w.y & 0xffffu) + CS[16+g+2] + zb[(g+2)&15];
                tile[r+3][tid] = AS[16+g+3]*bfu(w.y >> 16)     + CS[16+g+3] + zb[(g+3)&15];
                tile[r+4][tid] = AS[16+g+4]*bfu(w.z & 0xffffu) + CS[16+g+4] + zb[(g+4)&15];
                tile[r+5][tid] = AS[16+g+5]*bfu(w.z >> 16)     + CS[16+g+5] + zb[(g+5)&15];
                tile[r+6][tid] = AS[16+g+6]*bfu(w.w & 0xffffu) + CS[16+g+6] + zb[(g+6)&15];
                tile[r+7][tid] = AS[16+g+7]*bfu(w.w >> 16)     + CS[16+g+7] + zb[(g+7)&15];
            }
        }
        __syncthreads();
        for (int i = tid; i < 6400; i += 256) {
            int kk = i / 200, p = i - kk * 200;
            int adr = n * 204800 + (h * 32 + kk) * 3200 + t0 * 25 + p;
            float val = tile[kk][p] + (FIRST ? 0.f : out[adr]);
            out[adr] = val;
            if (LAST) tile[kk][p] = val;
        }
        if (LAST) {
            __syncthreads();
            int kk = tid >> 3, c8 = tid & 7;
            float sv = 0.f, qv = 0.f;
            for (int j = 0; j < 25; j++) {
                float xv = tile[kk][c8 * 25 + j];
                sv += xv; qv += xv * xv;
            }
            sv += __shfl_down(sv, 4, 8); sv += __shfl_down(sv, 2, 8); sv += __shfl_down(sv, 1, 8);
            qv += __shfl_down(qv, 4, 8); qv += __shfl_down(qv, 2, 8); qv += __shfl_down(qv, 1, 8);
            if ((tid & 7) == 0) {
                atomicAdd(&stout[h * 32 + kk], sv);
                atomicAdd(&stout[64 + h * 32 + kk], qv);
            }
        }
    }
}

// ---- K5: out = relu(bn(acc) + x), in place on d_out
__global__ __launch_bounds__(256) void k_final(
    const float* __restrict__ x, const float* __restrict__ go,
    const float* __restrict__ bo, const float* __restrict__ stout,
    float* __restrict__ out)
{
    __shared__ float ao[64], co[64];
    const int tid = threadIdx.x;
    if (tid < 64) {
        float m   = stout[tid] * (1.f / CNTF);
        float var = stout[64 + tid] * (1.f / CNTF) - m * m;
        float a   = go[tid] * rsqrtf(var + EPS);
        ao[tid] = a; co[tid] = bo[tid] - m * a;
    }
    __syncthreads();
    const float4* x4 = (const float4*)x;
    float4* o4 = (float4*)out;
    for (int i = blockIdx.x * 256 + tid; i < 6553600; i += gridDim.x * 256) {
        int k = (i / 800) & 63;
        float a = ao[k], c = co[k];
        float4 vo = o4[i], vx = x4[i];
        vo.x = fmaxf(fmaf(a, vo.x, c) + vx.x, 0.f);
        vo.y = fmaxf(fmaf(a, vo.y, c) + vx.y, 0.f);
        vo.z = fmaxf(fmaf(a, vo.z, c) + vx.z, 0.f);
        vo.w = fmaxf(fmaf(a, vo.w, c) + vx.w, 0.f);
        o4[i] = vo;
    }
}

extern "C" void kernel_launch(void* const* d_in, const int* in_sizes, int n_in,
                              void* d_out, int out_size, void* d_ws, size_t ws_size,
                              hipStream_t stream)
{
    const float* x     = (const float*)d_in[0];
    const float* PA    = (const float*)d_in[1];
    const float* Wd    = (const float*)d_in[2];
    const float* gd    = (const float*)d_in[4];
    const float* betad = (const float*)d_in[5];
    const float* Wsub  = (const float*)d_in[6];
    const float* gsub  = (const float*)d_in[8];
    const float* betas = (const float*)d_in[9];
    const float* gout  = (const float*)d_in[10];
    const float* betao = (const float*)d_in[11];
    float* out = (float*)d_out;

    unsigned short* xdp  = (unsigned short*)d_ws;            // 39.3 MB
    unsigned short* zbuf = xdp + (size_t)3 * XDP_ELEMS;      // 65.5 MB, reused per layer
    float* st    = (float*)(zbuf + (size_t)Z_ELEMS);
    float* AC    = st + 96;
    float* stq   = AC + 96;       // [3][160]
    float* stout = stq + 480;     // [128]
    float* Wtg   = stout + 128;   // [64][48] transposed W_down

    hipMemsetAsync(st, 0, 800 * sizeof(float), stream);

    k_prep   <<<1,   256, 0, stream>>>(Wd, Wtg);
    k_down3  <<<800, 256, 0, stream>>>(x, Wtg, xdp, st);
    k_findown<<<1,    64, 0, stream>>>(st, gd, betad, AC);

    for (int l = 0; l < 3; l++) {
        k_z_mfma<<<1024, 256, 0, stream>>>(xdp + (size_t)l * XDP_ELEMS, PA + l * 3125,
                                           Wsub + l * 1280, AC + l * 16, AC + 48 + l * 16,
                                           zbuf, stq + l * 160);
        if (l == 0)
            k_apply<1, 0><<<2048, 256, 0, stream>>>(zbuf, stq + l * 160, gsub + l * 80,
                                                    betas + l * 80, out, stout);
        else if (l == 1)
            k_apply<0, 0><<<2048, 256, 0, stream>>>(zbuf, stq + l * 160, gsub + l * 80,
                                                    betas + l * 80, out, stout);
        else
            k_apply<0, 1><<<2048, 256, 0, stream>>>(zbuf, stq + l * 160, gsub + l * 80,
                                                    betas + l * 80, out, stout);
    }
    k_final<<<2048, 256, 0, stream>>>(x, gout, betao, stout, out);
}

// Round 11
// 476.605 us; speedup vs baseline: 1.1311x; 1.1311x over previous
//
#include <hip/hip_runtime.h>

#define EPS  1e-5f
#define CNTF 409600.0f            // N*T*V
#define XDP_ELEMS 6553600         // per layer: 16384 nt * 400, layout [nt][u][16o]

typedef short bf16x8 __attribute__((ext_vector_type(8)));
typedef float f32x4  __attribute__((ext_vector_type(4)));

union FRAG { unsigned int u[4]; bf16x8 v; };

__device__ __forceinline__ float wave_sum(float v) {
#pragma unroll
    for (int off = 32; off > 0; off >>= 1)
        v += __shfl_down(v, off, 64);
    return v;
}

__device__ __forceinline__ float bfu(unsigned int u16) {
    union { unsigned int i; float f; } x;
    x.i = u16 << 16;
    return x.f;
}
__device__ __forceinline__ unsigned int f2bf(float f) {
    union { float f; unsigned int i; } u; u.f = f;
    unsigned int r = u.i + 0x7fff + ((u.i >> 16) & 1);
    return r >> 16;
}
__device__ __forceinline__ unsigned int packbf(float a, float b) {
    return f2bf(a) | (f2bf(b) << 16);
}

// register reshape: M-tile D-frag -> B2-frag via 4 packs + 4 shuffles.
// src lane (lr_s,lg_s) holds M[v=lr_s][c=4*lg_s+r]; dest lane needs
// M[v=lr][c=8q+i], q=lg&1 -> gather from lanes lr+16*2q and lr+16*(2q+1).
__device__ __forceinline__ bf16x8 reshapeM(const f32x4 d, int sA, int sB) {
    unsigned int pk01 = packbf(d[0], d[1]);
    unsigned int pk23 = packbf(d[2], d[3]);
    FRAG f;
    f.u[0] = __shfl(pk01, sA, 64);
    f.u[1] = __shfl(pk23, sA, 64);
    f.u[2] = __shfl(pk01, sB, 64);
    f.u[3] = __shfl(pk23, sB, 64);
    return f.v;
}

// ---- K0: transpose W_down into [c][48] so k_down3 can scalar-load it
__global__ __launch_bounds__(256) void k_prep(const float* __restrict__ Wd,
                                              float* __restrict__ Wtg)
{
    for (int j = threadIdx.x; j < 3072; j += 256) {
        int c = j / 48, k = j - c * 48;
        int l = k / 16, o = k - l * 16;
        Wtg[j] = Wd[l * 1024 + o * 64 + c];
    }
}

// ---- K1: conv_down all 3 layers (bias cancels in BN), bf16 xd + stats.
__global__ __launch_bounds__(256) void k_down3(
    const float* __restrict__ x, const float* __restrict__ Wtg,
    unsigned short* __restrict__ xdp, float* __restrict__ st /*96*/)
{
    __shared__ float bins[96];
    const int tid = threadIdx.x;
    if (tid < 96) bins[tid] = 0.f;
    __syncthreads();

    const int base = (blockIdx.x * 256 + tid) * 2;
    const int n = base / 3200, pb = base - n * 3200;
    const float* xb = x + n * 204800 + pb;

    float acc0[48], acc1[48];
#pragma unroll
    for (int k = 0; k < 48; k++) { acc0[k] = 0.f; acc1[k] = 0.f; }

    for (int c = 0; c < 64; c++) {
        float2 xv = *(const float2*)&xb[c * 3200];
        const float4* wr = (const float4*)(Wtg + c * 48);   // uniform -> s_load
#pragma unroll
        for (int q = 0; q < 12; q++) {
            float4 w = wr[q];
            acc0[4*q+0] += w.x * xv.x;  acc1[4*q+0] += w.x * xv.y;
            acc0[4*q+1] += w.y * xv.x;  acc1[4*q+1] += w.y * xv.y;
            acc0[4*q+2] += w.z * xv.x;  acc1[4*q+2] += w.z * xv.y;
            acc0[4*q+3] += w.w * xv.x;  acc1[4*q+3] += w.w * xv.y;
        }
    }
#pragma unroll
    for (int l = 0; l < 3; l++) {
        unsigned int pk0[8], pk1[8];
#pragma unroll
        for (int h = 0; h < 8; h++) {
            pk0[h] = packbf(acc0[l*16 + 2*h], acc0[l*16 + 2*h + 1]);
            pk1[h] = packbf(acc1[l*16 + 2*h], acc1[l*16 + 2*h + 1]);
        }
        uint4* dst = (uint4*)(xdp + (size_t)l * XDP_ELEMS + (size_t)base * 16);
        dst[0] = make_uint4(pk0[0], pk0[1], pk0[2], pk0[3]);
        dst[1] = make_uint4(pk0[4], pk0[5], pk0[6], pk0[7]);
        dst[2] = make_uint4(pk1[0], pk1[1], pk1[2], pk1[3]);
        dst[3] = make_uint4(pk1[4], pk1[5], pk1[6], pk1[7]);
    }

    const int lane = tid & 63;
#pragma unroll
    for (int k = 0; k < 48; k++) {
        float sv = wave_sum(acc0[k] + acc1[k]);
        float qv = wave_sum(acc0[k] * acc0[k] + acc1[k] * acc1[k]);
        if (lane == 0) { atomicAdd(&bins[k], sv); atomicAdd(&bins[48 + k], qv); }
    }
    __syncthreads();
    if (tid < 96) atomicAdd(&st[tid], bins[tid]);
}

// ---- K2: finalize down affines
__global__ __launch_bounds__(64) void k_findown(
    const float* __restrict__ st, const float* __restrict__ gd,
    const float* __restrict__ betad, float* __restrict__ AC)
{
    int t = threadIdx.x;
    if (t < 48) {
        float m   = st[t] * (1.f / CNTF);
        float var = st[48 + t] * (1.f / CNTF) - m * m;
        float a   = gd[t] * rsqrtf(var + EPS);
        AC[t]      = a;
        AC[48 + t] = betad[t] - a * m;
    }
}

// ---- K3: per-layer z stats via MFMA (no z materialization).
__global__ __launch_bounds__(256, 1) void k_zstats(
    const unsigned short* __restrict__ xd,   // [nt][u<25][16c] bf16
    const float* __restrict__ PAl,           // [5][25][25]
    const float* __restrict__ Wsl,           // [80][16]
    const float* __restrict__ Al, const float* __restrict__ Cl,
    float* __restrict__ stql)                // [160]
{
    __shared__ unsigned short xtile[4][512];
    __shared__ float bins[160];

    const int tid  = threadIdx.x;
    const int wave = tid >> 6, lane = tid & 63;
    const int lr = lane & 15, lg = lane >> 4;
    const int q = lg & 1;
    const int sA = lr + 16 * (2 * q), sB = lr + 16 * (2 * q + 1);

    *(uint4*)&xtile[tid >> 6][(tid & 63) * 8] = make_uint4(0, 0, 0, 0);
    for (int i = tid; i < 160; i += 256) bins[i] = 0.f;
    __syncthreads();

    bf16x8 Bfrag[5][2];
#pragma unroll
    for (int s = 0; s < 5; s++)
#pragma unroll
        for (int t = 0; t < 2; t++) {
            FRAG f;
            const int v = t * 16 + lr;
#pragma unroll
            for (int h = 0; h < 4; h++) {
                int u0 = 8 * lg + 2 * h, u1 = u0 + 1;
                float f0 = (v < 25 && u0 < 25) ? PAl[(s * 25 + v) * 25 + u0] : 0.f;
                float f1 = (v < 25 && u1 < 25) ? PAl[(s * 25 + v) * 25 + u1] : 0.f;
                f.u[h] = packbf(f0, f1);
            }
            Bfrag[s][t] = f.v;
        }

    bf16x8 Wfrag[5];
#pragma unroll
    for (int s = 0; s < 5; s++) {
        FRAG f;
#pragma unroll
        for (int h = 0; h < 4; h++) {
            int c0 = 8 * lg + 2 * h, c1 = c0 + 1;
            float f0 = (c0 < 16) ? Wsl[(s * 16 + lr) * 16 + c0] : 0.f;
            float f1 = (c1 < 16) ? Wsl[(s * 16 + lr) * 16 + c1] : 0.f;
            f.u[h] = packbf(f0, f1);
        }
        Wfrag[s] = f.v;
    }

    const float a_c = Al[lr], c_c = Cl[lr];

    f32x4 sacc[5] = {};
    f32x4 qacc[5] = {};
    const f32x4 zero = {};

    const int wid = blockIdx.x * 4 + wave;
    for (int k = 0; k < 4; k++) {
        const int nt = wid * 4 + k;
        if (lane < 50)
            *(uint4*)&xtile[wave][lane * 8] =
                *(const uint4*)(xd + (size_t)nt * 400 + lane * 8);
        __syncthreads();

        FRAG af;
#pragma unroll
        for (int h = 0; h < 4; h++) {
            int u0 = 8 * lg + 2 * h;
            float x0 = bfu(xtile[wave][u0 * 16 + lr]);
            float x1 = bfu(xtile[wave][(u0 + 1) * 16 + lr]);
            x0 = fmaxf(a_c * x0 + c_c, 0.f);
            x1 = fmaxf(a_c * x1 + c_c, 0.f);
            af.u[h] = packbf(x0, x1);
        }
        const bf16x8 A = af.v;

#pragma unroll
        for (int s = 0; s < 5; s++) {
            f32x4 d0 = __builtin_amdgcn_mfma_f32_16x16x32_bf16(A, Bfrag[s][0], zero, 0, 0, 0);
            f32x4 d1 = __builtin_amdgcn_mfma_f32_16x16x32_bf16(A, Bfrag[s][1], zero, 0, 0, 0);
            bf16x8 b2a = reshapeM(d0, sA, sB);
            bf16x8 b2b = reshapeM(d1, sA, sB);
            f32x4 z0 = __builtin_amdgcn_mfma_f32_16x16x32_bf16(Wfrag[s], b2a, zero, 0, 0, 0);
            f32x4 z1 = __builtin_amdgcn_mfma_f32_16x16x32_bf16(Wfrag[s], b2b, zero, 0, 0, 0);
            sacc[s] += z0; qacc[s] += z0 * z0;
            if (lr < 9) { sacc[s] += z1; qacc[s] += z1 * z1; }
        }
        __syncthreads();   // compute done before next staging overwrites
    }

#pragma unroll
    for (int s = 0; s < 5; s++)
#pragma unroll
        for (int r = 0; r < 4; r++) {
            float sv = sacc[s][r], qv = qacc[s][r];
            sv += __shfl_xor(sv, 1, 64); qv += __shfl_xor(qv, 1, 64);
            sv += __shfl_xor(sv, 2, 64); qv += __shfl_xor(qv, 2, 64);
            sv += __shfl_xor(sv, 4, 64); qv += __shfl_xor(qv, 4, 64);
            sv += __shfl_xor(sv, 8, 64); qv += __shfl_xor(qv, 8, 64);
            if (lr == 0) {
                atomicAdd(&bins[s * 16 + 4 * lg + r], sv);
                atomicAdd(&bins[80 + s * 16 + 4 * lg + r], qv);
            }
        }
    __syncthreads();
    for (int i = tid; i < 160; i += 256) atomicAdd(&stql[i], bins[i]);
}

// ---- K4: fold sub-BN affine into W (W2 = A*W, bf16) and constants into Cagg[64]
__global__ __launch_bounds__(256) void k_finsub(
    const float* __restrict__ stq,    // [3][160]
    const float* __restrict__ Wsub,   // [3][80][16]
    const float* __restrict__ gs, const float* __restrict__ betas,
    unsigned short* __restrict__ W2,  // [3][80][16] bf16 (A-scaled)
    float* __restrict__ Cagg)         // [64]
{
    __shared__ float As[240], Cs[240];
    const int tid = threadIdx.x;
    if (tid < 240) {
        int l = tid / 80, ch = tid - l * 80;
        float m   = stq[l * 160 + ch] * (1.f / CNTF);
        float var = stq[l * 160 + 80 + ch] * (1.f / CNTF) - m * m;
        float a   = gs[l * 80 + ch] * rsqrtf(var + EPS);
        As[tid] = a;
        Cs[tid] = betas[l * 80 + ch] - a * m;
    }
    __syncthreads();
    for (int i = tid; i < 3840; i += 256) {
        int l = i / 1280, r = i - l * 1280, ch = r / 16;
        W2[i] = (unsigned short)f2bf(As[l * 80 + ch] * Wsub[i]);
    }
    if (tid < 64) {
        int sIdx = tid >> 4, o = tid & 15;
        float c = 0.f;
        for (int l = 0; l < 3; l++)
            c += Cs[l * 80 + (sIdx + 1) * 16 + o] + Cs[l * 80 + o];
        Cagg[tid] = c;
    }
}

// ---- K5: fused 3-layer output via MFMA: recompute z, aggregate, write out once,
// and accumulate final-BN stats. PA fragments pre-packed in LDS.
__global__ __launch_bounds__(256, 1) void k_out_mfma(
    const unsigned short* __restrict__ xdp,  // [3][nt][u<25][16c]
    const float* __restrict__ PA,            // [3][5][25][25]
    const unsigned short* __restrict__ W2,   // [3][80][16] bf16
    const float* __restrict__ Cagg,          // [64]
    const float* __restrict__ AC,            // [96] down affines
    float* __restrict__ stout,               // [128]
    float* __restrict__ out)
{
    __shared__ unsigned int PAfr[30 * 64 * 4];     // 30 frags x 64 lanes x uint4
    __shared__ unsigned short xtile[4][3][512];
    __shared__ float bins[128];

    const int tid  = threadIdx.x;
    const int wave = tid >> 6, lane = tid & 63;
    const int lr = lane & 15, lg = lane >> 4;
    const int q = lg & 1;
    const int sA = lr + 16 * (2 * q), sB = lr + 16 * (2 * q + 1);

    // build PA fragments (30 x 64 entries), zero xtile, zero bins
    for (int e = tid; e < 1920; e += 256) {
        int frag = e >> 6, ln = e & 63;
        int l = frag / 10, rem = frag - l * 10;
        int s = rem >> 1, t = rem & 1;
        int elr = ln & 15, elg = ln >> 4;
        int v = t * 16 + elr;
        unsigned int u4[4];
#pragma unroll
        for (int h = 0; h < 4; h++) {
            int u0 = 8 * elg + 2 * h, u1 = u0 + 1;
            float f0 = (v < 25 && u0 < 25) ? PA[l * 3125 + (s * 25 + v) * 25 + u0] : 0.f;
            float f1 = (v < 25 && u1 < 25) ? PA[l * 3125 + (s * 25 + v) * 25 + u1] : 0.f;
            u4[h] = packbf(f0, f1);
        }
        *(uint4*)&PAfr[e * 4] = make_uint4(u4[0], u4[1], u4[2], u4[3]);
    }
    for (int i = tid; i < 768; i += 256)
        *(uint4*)&xtile[0][0][i * 8] = make_uint4(0, 0, 0, 0);
    if (tid < 128) bins[tid] = 0.f;

    // persistent pre-scaled W fragments (c>=16 zero)
    bf16x8 Wf[3][5];
#pragma unroll
    for (int l = 0; l < 3; l++)
#pragma unroll
        for (int s = 0; s < 5; s++) {
            FRAG f;
            if (lg < 2)
                *(uint4*)f.u = *(const uint4*)(W2 + ((l * 5 + s) * 16 + lr) * 16 + lg * 8);
            else
                *(uint4*)f.u = make_uint4(0, 0, 0, 0);
            Wf[l][s] = f.v;
        }

    float a3[3], c3[3];
#pragma unroll
    for (int l = 0; l < 3; l++) { a3[l] = AC[l * 16 + lr]; c3[l] = AC[48 + l * 16 + lr]; }

    float cagg[4][4];
#pragma unroll
    for (int sI = 0; sI < 4; sI++)
#pragma unroll
        for (int r = 0; r < 4; r++) cagg[sI][r] = Cagg[sI * 16 + 4 * lg + r];

    f32x4 ss[4] = {}, qq[4] = {};
    const f32x4 zero = {};
    __syncthreads();   // PAfr ready

    const int wid = blockIdx.x * 4 + wave;
    for (int k = 0; k < 4; k++) {
        const int nt = wid * 4 + k;
        // stage 3 layers of this nt (wave-private tiles)
#pragma unroll
        for (int it = 0; it < 3; it++) {
            int j = lane + it * 64;
            if (j < 150) {
                int l = j / 50, off = j - l * 50;
                *(uint4*)&xtile[wave][l][off * 8] =
                    *(const uint4*)(xdp + (size_t)l * XDP_ELEMS + (size_t)nt * 400 + off * 8);
            }
        }
        __syncthreads();

        f32x4 acc0[4] = {}, acc1[4] = {};
#pragma unroll
        for (int l = 0; l < 3; l++) {
            FRAG af;
#pragma unroll
            for (int h = 0; h < 4; h++) {
                int u0 = 8 * lg + 2 * h;
                float x0 = bfu(xtile[wave][l][u0 * 16 + lr]);
                float x1 = bfu(xtile[wave][l][(u0 + 1) * 16 + lr]);
                x0 = fmaxf(a3[l] * x0 + c3[l], 0.f);
                x1 = fmaxf(a3[l] * x1 + c3[l], 0.f);
                af.u[h] = packbf(x0, x1);
            }
            const bf16x8 A = af.v;

            f32x4 z0a, z0b;
#pragma unroll
            for (int s = 0; s < 5; s++) {
                FRAG bfA, bfB;
                *(uint4*)bfA.u = *(const uint4*)&PAfr[(((l * 5 + s) * 2 + 0) * 64 + lane) * 4];
                *(uint4*)bfB.u = *(const uint4*)&PAfr[(((l * 5 + s) * 2 + 1) * 64 + lane) * 4];
                f32x4 d0 = __builtin_amdgcn_mfma_f32_16x16x32_bf16(A, bfA.v, zero, 0, 0, 0);
                f32x4 d1 = __builtin_amdgcn_mfma_f32_16x16x32_bf16(A, bfB.v, zero, 0, 0, 0);
                bf16x8 b2a = reshapeM(d0, sA, sB);
                bf16x8 b2b = reshapeM(d1, sA, sB);
                f32x4 za = __builtin_amdgcn_mfma_f32_16x16x32_bf16(Wf[l][s], b2a, zero, 0, 0, 0);
                f32x4 zb = __builtin_amdgcn_mfma_f32_16x16x32_bf16(Wf[l][s], b2b, zero, 0, 0, 0);
                if (s == 0) { z0a = za; z0b = zb; }
                else {
                    acc0[s - 1] += za + z0a;
                    acc1[s - 1] += zb + z0b;
                }
            }
        }

        // write out + accumulate stats
        float* obase = out + (nt >> 7) * 204800 + (nt & 127) * 25;
#pragma unroll
        for (int sI = 0; sI < 4; sI++) {
#pragma unroll
            for (int r = 0; r < 4; r++) {
                int ch = sI * 16 + 4 * lg + r;
                float v0 = acc0[sI][r] + cagg[sI][r];
                obase[ch * 3200 + lr] = v0;
                float v1 = acc1[sI][r] + cagg[sI][r];
                float use1 = (lr < 9) ? v1 : 0.f;
                if (lr < 9) obase[ch * 3200 + 16 + lr] = v1;
                ss[sI][r] += v0 + use1;
                qq[sI][r] += v0 * v0 + use1 * use1;
            }
        }
        __syncthreads();   // all reads of xtile done before next staging
    }

#pragma unroll
    for (int sI = 0; sI < 4; sI++)
#pragma unroll
        for (int r = 0; r < 4; r++) {
            float sv = ss[sI][r], qv = qq[sI][r];
            sv += __shfl_xor(sv, 1, 64); qv += __shfl_xor(qv, 1, 64);
            sv += __shfl_xor(sv, 2, 64); qv += __shfl_xor(qv, 2, 64);
            sv += __shfl_xor(sv, 4, 64); qv += __shfl_xor(qv, 4, 64);
            sv += __shfl_xor(sv, 8, 64); qv += __shfl_xor(qv, 8, 64);
            if (lr == 0) {
                atomicAdd(&bins[sI * 16 + 4 * lg + r], sv);
                atomicAdd(&bins[64 + sI * 16 + 4 * lg + r], qv);
            }
        }
    __syncthreads();
    if (tid < 128) atomicAdd(&stout[tid], bins[tid]);
}

// ---- K6: out = relu(bn(acc) + x), in place on d_out
__global__ __launch_bounds__(256) void k_final(
    const float* __restrict__ x, const float* __restrict__ go,
    const float* __restrict__ bo, const float* __restrict__ stout,
    float* __restrict__ out)
{
    __shared__ float ao[64], co[64];
    const int tid = threadIdx.x;
    if (tid < 64) {
        float m   = stout[tid] * (1.f / CNTF);
        float var = stout[64 + tid] * (1.f / CNTF) - m * m;
        float a   = go[tid] * rsqrtf(var + EPS);
        ao[tid] = a; co[tid] = bo[tid] - m * a;
    }
    __syncthreads();
    const float4* x4 = (const float4*)x;
    float4* o4 = (float4*)out;
    for (int i = blockIdx.x * 256 + tid; i < 6553600; i += gridDim.x * 256) {
        int k = (i / 800) & 63;
        float a = ao[k], c = co[k];
        float4 vo = o4[i], vx = x4[i];
        vo.x = fmaxf(fmaf(a, vo.x, c) + vx.x, 0.f);
        vo.y = fmaxf(fmaf(a, vo.y, c) + vx.y, 0.f);
        vo.z = fmaxf(fmaf(a, vo.z, c) + vx.z, 0.f);
        vo.w = fmaxf(fmaf(a, vo.w, c) + vx.w, 0.f);
        o4[i] = vo;
    }
}

extern "C" void kernel_launch(void* const* d_in, const int* in_sizes, int n_in,
                              void* d_out, int out_size, void* d_ws, size_t ws_size,
                              hipStream_t stream)
{
    const float* x     = (const float*)d_in[0];
    const float* PA    = (const float*)d_in[1];
    const float* Wd    = (const float*)d_in[2];
    const float* gd    = (const float*)d_in[4];
    const float* betad = (const float*)d_in[5];
    const float* Wsub  = (const float*)d_in[6];
    const float* gsub  = (const float*)d_in[8];
    const float* betas = (const float*)d_in[9];
    const float* gout  = (const float*)d_in[10];
    const float* betao = (const float*)d_in[11];
    float* out = (float*)d_out;

    unsigned short* xdp = (unsigned short*)d_ws;             // 39.3 MB
    float* st    = (float*)(xdp + (size_t)3 * XDP_ELEMS);
    float* AC    = st + 96;
    float* stq   = AC + 96;       // [3][160]
    float* stout = stq + 480;     // [128]
    float* Wtg   = stout + 128;   // [64][48]
    float* Cagg  = Wtg + 3072;    // [64]
    unsigned short* W2 = (unsigned short*)(Cagg + 64);  // [3][80][16] bf16

    hipMemsetAsync(st, 0, (96 + 96 + 480 + 128) * sizeof(float), stream);

    k_prep   <<<1,   256, 0, stream>>>(Wd, Wtg);
    k_down3  <<<800, 256, 0, stream>>>(x, Wtg, xdp, st);
    k_findown<<<1,    64, 0, stream>>>(st, gd, betad, AC);

    for (int l = 0; l < 3; l++)
        k_zstats<<<1024, 256, 0, stream>>>(xdp + (size_t)l * XDP_ELEMS, PA + l * 3125,
                                           Wsub + l * 1280, AC + l * 16, AC + 48 + l * 16,
                                           stq + l * 160);
    k_finsub  <<<1,    256, 0, stream>>>(stq, Wsub, gsub, betas, W2, Cagg);
    k_out_mfma<<<1024, 256, 0, stream>>>(xdp, PA, W2, Cagg, AC, stout, out);
    k_final   <<<2048, 256, 0, stream>>>(x, gout, betao, stout, out);
}